// Round 1
// 403.135 us; speedup vs baseline: 1.0118x; 1.0118x over previous
//
#include <hip/hip_runtime.h>
#include <hip/hip_bf16.h>
#include <stdint.h>

// out[2048,256] = x[2048,32768] @ W[32768,256],
// W[k,r] = U0[k&31, r] * U1[(k>>5)&31, r] * U2[k>>10, r]
//
// Plan: kernel 1 materializes W^T in bf16, tiled+XOR-swizzled so the GEMM can
// stage it with async global_load_lds (identity copy) and read MFMA fragments
// conflict-free. Kernel 2: 128x128-tile split-K=16 bf16 MFMA GEMM, fp32 x
// converted to bf16 in-register while staging A, atomicAdd fp32 epilogue.
//
// R1 change: XCD-pair blockIdx remap in gemm. The two W-panel blocks (p=0/1)
// that read the SAME 1 MB x chunk previously had consecutive bids -> landed
// on different XCDs (round-robin bid%8) -> x fetched twice from HBM (512 MB).
// Now they are bids b and b+8 -> same XCD, concurrent, lockstep workload ->
// second block's x reads hit the XCD-local L2. x HBM traffic ~512->~256 MB.

#define K_DIM 32768
#define R_DIM 256
#define M_DIM 2048
#define BM 128
#define BN 128
#define BK 64
#define SK 16
#define KC (K_DIM / SK)   // 2048 K per block
#define NKI (KC / BK)     // 32 iterations

typedef float f32x4 __attribute__((ext_vector_type(4)));
typedef short s16x8 __attribute__((ext_vector_type(8)));

// pack two fp32 -> two bf16 (round-half-up via +0x8000, then v_perm byte pick)
__device__ __forceinline__ uint32_t pack2_bf16(float a, float b) {
    uint32_t ua = __builtin_bit_cast(uint32_t, a) + 0x8000u;
    uint32_t ub = __builtin_bit_cast(uint32_t, b) + 0x8000u;
    // result: low 16 = hi16(a), high 16 = hi16(b)
    return __builtin_amdgcn_perm(ub, ua, 0x07060302u);
}

__device__ __forceinline__ void async_load16(const void* g, void* lds) {
    __builtin_amdgcn_global_load_lds(
        (const __attribute__((address_space(1))) void*)g,
        (__attribute__((address_space(3))) void*)lds, 16, 0, 0);
}

// ---------------------------------------------------------------------------
// Kernel 1: W^T (bf16), tiled layout:
//   panel p (0..1, 128 r each) x ktile t (0..511, 64 k each):
//     tile base (16B chunks): (p*512 + t)*1024
//     within tile: row r' (0..127) holds 64 k as 8 chunks of 8 bf16,
//     chunk c stored at position c ^ (r'&7)  (XOR swizzle for LDS banks)
// One thread per 16B chunk: 2*512*128*8 = 1,048,576 threads.
// ---------------------------------------------------------------------------
__global__ __launch_bounds__(256) void wgen_kernel(
        const float* __restrict__ U0, const float* __restrict__ U1,
        const float* __restrict__ U2, uint16_t* __restrict__ Wsw) {
    uint32_t tid   = blockIdx.x * 256u + threadIdx.x;  // [0, 1<<20)
    uint32_t c_pos = tid & 7u;
    uint32_t r     = (tid >> 3) & 127u;
    uint32_t t     = (tid >> 10) & 511u;
    uint32_t p     = tid >> 19;
    uint32_t c     = c_pos ^ (r & 7u);        // source chunk for this position
    uint32_t rg    = p * 128u + r;            // global r in [0,256)
    uint32_t kbase = t * 64u + c * 8u;
    uint32_t i1    = (kbase >> 5) & 31u;      // constant across the 8 elems
    uint32_t i2    = kbase >> 10;
    uint32_t i0b   = kbase & 31u;             // i0 = i0b + e (no carry, e<8)
    float u12 = U1[i1 * 256u + rg] * U2[i2 * 256u + rg];
    float w[8];
#pragma unroll
    for (int e = 0; e < 8; ++e)
        w[e] = U0[(i0b + (uint32_t)e) * 256u + rg] * u12;
    uint32_t q0 = pack2_bf16(w[0], w[1]);
    uint32_t q1 = pack2_bf16(w[2], w[3]);
    uint32_t q2 = pack2_bf16(w[4], w[5]);
    uint32_t q3 = pack2_bf16(w[6], w[7]);
    *(uint4*)(Wsw + (size_t)tid * 8u) = make_uint4(q0, q1, q2, q3);
}

// ---------------------------------------------------------------------------
// Kernel 2: GEMM. 256 threads = 4 waves (2x2 over 128x128 tile, 64x64/wave,
// 4x4 grid of 16x16x32 bf16 MFMA). Grid: 16 mblk x 16 sk x 2 panel = 512.
// ---------------------------------------------------------------------------
__global__ __launch_bounds__(256, 3) void gemm_kernel(
        const float* __restrict__ x, const uint16_t* __restrict__ Wsw,
        float* __restrict__ out) {
    __shared__ uint16_t As[BM * 64];   // 16 KB bf16, swizzled chunks
    __shared__ uint16_t Bs[BN * 64];   // 16 KB bf16, swizzled chunks

    const uint32_t bid  = blockIdx.x;
    // XCD-pair remap: blocks b and b+8 share the same x tile (differ only in
    // the W panel p). Default dispatch round-robins bid%8 across XCDs, so b
    // and b+8 land on the SAME XCD and run concurrently -> the pair's second
    // x read hits that XCD's L2 instead of HBM.
    // Bijection check: (bid&7, bid>>3 bit0 -> p, bid>>4) covers
    // [0,8)x[0,2)x[0,32); idx recombines to [0,256) -> (sk, mblk) unique.
    const uint32_t p    = (bid >> 3) & 1u;                // W column panel
    const uint32_t idx  = (bid & 7u) | ((bid >> 4) << 3); // 0..255
    const uint32_t sk   = idx & 15u;                      // K split
    const uint32_t mblk = idx >> 4;                       // x row block

    const uint32_t tid  = threadIdx.x;
    const uint32_t lane = tid & 63u;
    const uint32_t wave = tid >> 6;

    // ---- A staging (fp32 global -> bf16 swizzled LDS via registers) ----
    const uint32_t ac   = tid & 7u;    // k-chunk (8 floats)
    const uint32_t arow = tid >> 3;    // row group base [0,32), rows +{0,32,64,96}
    const uint32_t aswz = (ac ^ (arow & 7u)) * 8u;  // uint16 offset in row
    const float* xg = x + (size_t)(mblk * BM + arow) * K_DIM + sk * KC + ac * 8u;

    // ---- B staging (async identity copy of pre-swizzled tiles) ----
    const uint16_t* wg_base = Wsw + (size_t)(p * 512u + sk * 32u) * 8192u;

    // ---- fragment addressing ----
    const uint32_t mloc = lane & 15u;
    const uint32_t quad = lane >> 4;
    const uint32_t wm = wave >> 1, wn = wave & 1u;
    const uint32_t sw0 = ((quad) ^ (mloc & 7u)) * 8u;       // ks=0 chunk
    const uint32_t sw1 = ((4u + quad) ^ (mloc & 7u)) * 8u;  // ks=1 chunk
    const uint32_t aRow0 = (wm * 64u + mloc) * 64u;
    const uint32_t bRow0 = (wn * 64u + mloc) * 64u;

    f32x4 acc[4][4];
#pragma unroll
    for (int i = 0; i < 4; ++i)
#pragma unroll
        for (int j = 0; j < 4; ++j) acc[i][j] = (f32x4){0.f, 0.f, 0.f, 0.f};

    for (uint32_t it = 0; it < NKI; ++it) {
        // B: 4 x 16B per thread, async global->LDS (wave-uniform LDS base)
        const uint16_t* wg_tile = wg_base + (size_t)it * 8192u;
#pragma unroll
        for (int j = 0; j < 4; ++j) {
            uint32_t instr = wave * 4u + (uint32_t)j;
            const uint16_t* g = wg_tile + ((size_t)instr * 64u + lane) * 8u;
            async_load16((const void*)g, (void*)&Bs[instr * 512u]);
        }
        // A: 8 rows x 256B per wave, register convert, swizzled ds_write_b128
#pragma unroll
        for (int j = 0; j < 4; ++j) {
            const float* g = xg + (size_t)(j * 32) * K_DIM + it * BK;
            f32x4 v0 = *(const f32x4*)(g);
            f32x4 v1 = *(const f32x4*)(g + 4);
            uint32_t q0 = pack2_bf16(v0[0], v0[1]);
            uint32_t q1 = pack2_bf16(v0[2], v0[3]);
            uint32_t q2 = pack2_bf16(v1[0], v1[1]);
            uint32_t q3 = pack2_bf16(v1[2], v1[3]);
            *(uint4*)(&As[(arow + (uint32_t)j * 32u) * 64u + aswz]) =
                make_uint4(q0, q1, q2, q3);
        }
        __syncthreads();

#pragma unroll
        for (int ks = 0; ks < 2; ++ks) {
            const uint32_t sw = ks ? sw1 : sw0;
            s16x8 af[4], bf[4];
#pragma unroll
            for (int t = 0; t < 4; ++t)
                af[t] = *(const s16x8*)(&As[aRow0 + (uint32_t)t * 1024u + sw]);
#pragma unroll
            for (int t = 0; t < 4; ++t)
                bf[t] = *(const s16x8*)(&Bs[bRow0 + (uint32_t)t * 1024u + sw]);
#pragma unroll
            for (int mt = 0; mt < 4; ++mt)
#pragma unroll
                for (int nt = 0; nt < 4; ++nt)
                    acc[mt][nt] = __builtin_amdgcn_mfma_f32_16x16x32_bf16(
                        af[mt], bf[nt], acc[mt][nt], 0, 0, 0);
        }
        __syncthreads();
    }

    // epilogue: atomic accumulate partial tile (split-K)
    const uint32_t orow0 = mblk * BM + wm * 64u + quad * 4u;
    const uint32_t ocol0 = p * BN + wn * 64u + mloc;
#pragma unroll
    for (int mt = 0; mt < 4; ++mt) {
#pragma unroll
        for (int nt = 0; nt < 4; ++nt) {
            float* po = out + (size_t)(orow0 + (uint32_t)mt * 16u) * R_DIM +
                        ocol0 + (uint32_t)nt * 16u;
#pragma unroll
            for (int i = 0; i < 4; ++i)
                atomicAdd(po + (size_t)i * R_DIM, acc[mt][nt][i]);
        }
    }
}

extern "C" void kernel_launch(void* const* d_in, const int* in_sizes, int n_in,
                              void* d_out, int out_size, void* d_ws, size_t ws_size,
                              hipStream_t stream) {
    const float* x  = (const float*)d_in[0];
    const float* U0 = (const float*)d_in[1];
    const float* U1 = (const float*)d_in[2];
    const float* U2 = (const float*)d_in[3];
    float* out = (float*)d_out;
    uint16_t* Wsw = (uint16_t*)d_ws;   // needs 32768*256*2 = 16 MiB

    // zero output (harness poisons with 0xAA before every replay)
    hipMemsetAsync(d_out, 0, (size_t)out_size * sizeof(float), stream);
    // materialize swizzled W^T in bf16
    wgen_kernel<<<4096, 256, 0, stream>>>(U0, U1, U2, Wsw);
    // split-K MFMA GEMM with atomic reduce
    gemm_kernel<<<512, 256, 0, stream>>>(x, Wsw, out);
}